// Round 3
// baseline (400.694 us; speedup 1.0000x reference)
//
#include <hip/hip_runtime.h>

#define TWOPI_256 0.024543692606170259f  // 2*pi/256

// ---------------- Kernel 1a: stage A (W-DFT), per (img, 64-row chunk) -------------
// P[h][k] = sum_w x[h][w] e^{-2pi i k w/256}, k in [0,16)
// Pg layout: [img][k][h] float2
// 2048 blocks x 256 threads; thread = (rg in [0,16), k in [0,16)) owns rows rg*4..+3.
// No LDS staging for x: the 16 k-lanes of a row group issue identical addresses,
// which merge in-wave; L1 serves the 16x reuse (4 KB working set per block).
__global__ __launch_bounds__(256) void k1a_wdft(const float* __restrict__ x,
                                                float2* __restrict__ Pg) {
  const int blk = blockIdx.x;
  const int img = blk >> 2, hc = blk & 3;
  const int tid = threadIdx.x;

  __shared__ float tabc[256], tabs[256];
  {
    float s, c;
    sincosf((float)tid * TWOPI_256, &s, &c);
    tabc[tid] = c;
    tabs[tid] = s;
  }
  __syncthreads();

  const int k = tid & 15, rg = tid >> 4;
  const int h0 = hc * 64 + rg * 4;
  const float* rowp = x + ((size_t)img << 16) + (size_t)h0 * 256;
  const float4* r0 = (const float4*)rowp;
  const float4* r1 = (const float4*)(rowp + 256);
  const float4* r2 = (const float4*)(rowp + 512);
  const float4* r3 = (const float4*)(rowp + 768);

  const float cr = tabc[k], sr = tabs[k];
  float accr[4] = {0.f, 0.f, 0.f, 0.f}, acci[4] = {0.f, 0.f, 0.f, 0.f};

  for (int wc = 0; wc < 16; ++wc) {
    const int tw = (k * wc * 16) & 255;  // refresh from exact table every 16 w
    float c = tabc[tw], s = tabs[tw];
#pragma unroll
    for (int sc = 0; sc < 4; ++sc) {
      const int fi = wc * 4 + sc;
      const float4 a0 = r0[fi], a1 = r1[fi], a2 = r2[fi], a3 = r3[fi];
      const float xv[4][4] = {{a0.x, a1.x, a2.x, a3.x},
                              {a0.y, a1.y, a2.y, a3.y},
                              {a0.z, a1.z, a2.z, a3.z},
                              {a0.w, a1.w, a2.w, a3.w}};
#pragma unroll
      for (int wi = 0; wi < 4; ++wi) {
#pragma unroll
        for (int i = 0; i < 4; ++i) {
          accr[i] += xv[wi][i] * c;
          acci[i] -= xv[wi][i] * s;
        }
        const float cn = c * cr - s * sr;
        const float sn = s * cr + c * sr;
        c = cn; s = sn;
      }
    }
  }

  float2* dst = Pg + (size_t)((img * 16 + k) * 256 + h0);
  *(float4*)dst       = make_float4(accr[0], acci[0], accr[1], acci[1]);
  *(float4*)(dst + 2) = make_float4(accr[2], acci[2], accr[3], acci[3]);
}

// ---------------- Kernel 1b: stage B (H-DFT 256 -> 32 modes), per img -------------
// Xm[t][k] = sum_h P[h][k] e^{-2pi i ky_t h/256}, ky_t = t (t<16) or 240+(t-16)
// Xm layout: [t][k][ci][b] float2
__global__ __launch_bounds__(256) void k1b_hdft(const float2* __restrict__ Pg,
                                                float2* __restrict__ Xm) {
  const int img = blockIdx.x;
  const int tid = threadIdx.x;

  __shared__ float tabc[256], tabs[256];
  __shared__ float2 Ps[16][258];  // padded: k-stride 258 float2 -> conflict-free

  {
    float s, c;
    sincosf((float)tid * TWOPI_256, &s, &c);
    tabc[tid] = c;
    tabs[tid] = s;
  }
  {
    const float4* src = (const float4*)(Pg + ((size_t)img << 12));
#pragma unroll
    for (int j = 0; j < 8; ++j) {
      const int f = tid + j * 256;           // float4 index in [0,2048)
      const int kk = f >> 7, hp = (f & 127) << 1;
      *(float4*)&Ps[kk][hp] = src[f];
    }
  }
  __syncthreads();

  const int t = tid >> 3, k2 = tid & 7;      // thread: one t, k in {k2, k2+8}
  const int kyv = (t < 16) ? t : (t + 224);
  const float cr = tabc[kyv], sr = tabs[kyv];
  float c = 1.f, s = 0.f;
  float X0r = 0.f, X0i = 0.f, X1r = 0.f, X1i = 0.f;
  for (int h = 0; h < 256; h += 2) {
    const float4 p0 = *(const float4*)&Ps[k2][h];
    const float4 p1 = *(const float4*)&Ps[k2 + 8][h];
    X0r += p0.x * c + p0.y * s; X0i += p0.y * c - p0.x * s;
    X1r += p1.x * c + p1.y * s; X1i += p1.y * c - p1.x * s;
    float cn = c * cr - s * sr, sn = s * cr + c * sr; c = cn; s = sn;
    X0r += p0.z * c + p0.w * s; X0i += p0.w * c - p0.z * s;
    X1r += p1.z * c + p1.w * s; X1i += p1.w * c - p1.z * s;
    cn = c * cr - s * sr; sn = s * cr + c * sr; c = cn; s = sn;
  }
  const int ci = img & 63, b = img >> 6;
  Xm[((t * 16 + k2) * 64 + ci) * 8 + b]     = make_float2(X0r, X0i);
  Xm[((t * 16 + k2 + 8) * 64 + ci) * 8 + b] = make_float2(X1r, X1i);
}

// ---------------- Kernel 2: per (t,k): channel mixing + pair products + scaling ----
// Am layout: [b][o][t][k] float2, scaled by alpha_k = (k==0?1:2)/65536
__global__ __launch_bounds__(256) void k2_mix(const float2* __restrict__ Xm,
                                              const float* __restrict__ w1r,
                                              const float* __restrict__ w1i,
                                              const float* __restrict__ w2r,
                                              const float* __restrict__ w2i,
                                              float2* __restrict__ Am) {
  const int blk = blockIdx.x;  // t*16 + k
  const int t = blk >> 4, k = blk & 15;
  const int tp = t & 15;
  const float* __restrict__ wr = (t < 16) ? w1r : w2r;
  const float* __restrict__ wi = (t < 16) ? w1i : w2i;
  const int tid = threadIdx.x;

  __shared__ float2 Xs[64][8];  // [i][b]
  __shared__ float2 Cb[64][8];  // [o][b]

  {
    const float2* src = Xm + ((size_t)blk << 9);
    float2* dst = &Xs[0][0];
    dst[tid] = src[tid];
    dst[tid + 256] = src[tid + 256];
  }
  __syncthreads();

  for (int n = tid; n < 480; n += 256) {
    const int o = n >> 3, bb = n & 7;
    const int wofs = o * 256 + tp * 16 + k;
    float ar = 0.f, ai = 0.f;
#pragma unroll 4
    for (int i = 0; i < 64; ++i) {
      const float wrv = wr[i * 15360 + wofs];  // (i*60+o)*256 + tp*16 + k
      const float wiv = wi[i * 15360 + wofs];
      const float2 xv = Xs[i][bb];
      ar += xv.x * wrv - xv.y * wiv;
      ai += xv.x * wiv + xv.y * wrv;
    }
    Cb[o][bb] = make_float2(ar, ai);
  }
  __syncthreads();
  if (tid < 32) {
    const int p = tid >> 3, bb = tid & 7;
    const float2 u = Cb[2 * p][bb], v = Cb[2 * p + 1][bb];
    Cb[60 + p][bb] = make_float2(u.x * v.x - u.y * v.y, u.x * v.y + u.y * v.x);
  }
  __syncthreads();
  const float alpha = (k == 0 ? 1.f : 2.f) * (1.f / 65536.f);
#pragma unroll
  for (int n = tid; n < 512; n += 256) {
    const int o = n >> 3, bb = n & 7;
    const float2 v = Cb[o][bb];
    Am[(((size_t)(bb * 64 + o)) * 32 + t) * 16 + k] = make_float2(v.x * alpha, v.y * alpha);
  }
}

// ---------------- Kernel 3: per (b,o,h-half): inverse H-DFT then real inverse W ---
__device__ __forceinline__ unsigned int bfp(float a) {
  return (__float_as_uint(a) + 0x8000u) >> 16;
}

__global__ __launch_bounds__(256) void k3_inv(const float2* __restrict__ Am,
                                             float* __restrict__ out) {
  const int blk = blockIdx.x;          // (b*64+o)*2 + hc
  const int bo = blk >> 1, hc = blk & 1, h0 = hc << 7;
  const int tid = threadIdx.x;

  __shared__ float tabc[256], tabs[256];
  __shared__ float2 Ams[32][16];
  __shared__ unsigned short Zt[32][136];  // bf16; row 2k = Re(Z[k]), 2k+1 = Im; cols = h-local
  __shared__ unsigned short Tt[32][264];  // bf16; row 2k = cos(kw), 2k+1 = -sin(kw)

  {
    float s, c;
    sincosf((float)tid * TWOPI_256, &s, &c);
    tabc[tid] = c;
    tabs[tid] = s;
  }
  ((float4*)&Ams[0][0])[tid] = ((const float4*)(Am + ((size_t)bo << 9)))[tid];
  __syncthreads();

#pragma unroll
  for (int j = 0; j < 32; ++j) {
    const int idx = ((j >> 1) * tid) & 255;
    const float val = (j & 1) ? -tabs[idx] : tabc[idx];
    Tt[j][tid] = (unsigned short)bfp(val);
  }

  // Stage D: Z[h][k] = sum_t Am[t][k] e^{+2pi i ky_t h/256}; thread = (hg, kg): 2h x 4k
  const int hg = tid >> 2, kg = tid & 3;
  float Zr[2][4], Zi[2][4];
#pragma unroll
  for (int i = 0; i < 2; ++i)
#pragma unroll
    for (int j = 0; j < 4; ++j) { Zr[i][j] = 0.f; Zi[i][j] = 0.f; }
  float ch[2], sh[2], crh[2], srh[2];
#pragma unroll
  for (int i = 0; i < 2; ++i) {
    const int h = h0 + hg * 2 + i;
    crh[i] = tabc[h];
    srh[i] = tabs[h];
    ch[i] = 1.f;
    sh[i] = 0.f;
  }
  for (int t = 0; t < 32; ++t) {
    if (t == 16) {
#pragma unroll
      for (int i = 0; i < 2; ++i) {
        const int idx = (240 * (h0 + hg * 2 + i)) & 255;
        ch[i] = tabc[idx];
        sh[i] = tabs[idx];
      }
    }
    const float4 a01 = *(const float4*)&Ams[t][kg * 4];
    const float4 a23 = *(const float4*)&Ams[t][kg * 4 + 2];
    const float Ar[4] = {a01.x, a01.z, a23.x, a23.z};
    const float Ai[4] = {a01.y, a01.w, a23.y, a23.w};
#pragma unroll
    for (int i = 0; i < 2; ++i) {
#pragma unroll
      for (int j = 0; j < 4; ++j) {
        Zr[i][j] += Ar[j] * ch[i] - Ai[j] * sh[i];
        Zi[i][j] += Ar[j] * sh[i] + Ai[j] * ch[i];
      }
      const float cn = ch[i] * crh[i] - sh[i] * srh[i];
      const float sn = sh[i] * crh[i] + ch[i] * srh[i];
      ch[i] = cn;
      sh[i] = sn;
    }
  }
#pragma unroll
  for (int j = 0; j < 4; ++j) {
    const int kk = kg * 4 + j;
    *(unsigned int*)&Zt[2 * kk][2 * hg]     = bfp(Zr[0][j]) | (bfp(Zr[1][j]) << 16);
    *(unsigned int*)&Zt[2 * kk + 1][2 * hg] = bfp(Zi[0][j]) | (bfp(Zi[1][j]) << 16);
  }
  __syncthreads();

  // Stage E: out[h][w] = sum_j Z[j][h] * T[j][w]; thread tile 8h x 8w, 2 w-passes
  const int wg = tid & 15, hg2 = tid >> 4;
  float* outp = out + ((size_t)bo << 16);
#pragma unroll
  for (int wp = 0; wp < 2; ++wp) {
    float acc[8][8];
#pragma unroll
    for (int ii = 0; ii < 8; ++ii)
#pragma unroll
      for (int ww = 0; ww < 8; ++ww) acc[ii][ww] = 0.f;
    for (int j = 0; j < 32; ++j) {
      const uint4 zp = *(const uint4*)&Zt[j][hg2 * 8];
      float zv[8];
      zv[0] = __uint_as_float(zp.x << 16);
      zv[1] = __uint_as_float(zp.x & 0xffff0000u);
      zv[2] = __uint_as_float(zp.y << 16);
      zv[3] = __uint_as_float(zp.y & 0xffff0000u);
      zv[4] = __uint_as_float(zp.z << 16);
      zv[5] = __uint_as_float(zp.z & 0xffff0000u);
      zv[6] = __uint_as_float(zp.w << 16);
      zv[7] = __uint_as_float(zp.w & 0xffff0000u);
      const uint4 tq = *(const uint4*)&Tt[j][wp * 128 + wg * 8];
      float tv[8];
      tv[0] = __uint_as_float(tq.x << 16);
      tv[1] = __uint_as_float(tq.x & 0xffff0000u);
      tv[2] = __uint_as_float(tq.y << 16);
      tv[3] = __uint_as_float(tq.y & 0xffff0000u);
      tv[4] = __uint_as_float(tq.z << 16);
      tv[5] = __uint_as_float(tq.z & 0xffff0000u);
      tv[6] = __uint_as_float(tq.w << 16);
      tv[7] = __uint_as_float(tq.w & 0xffff0000u);
#pragma unroll
      for (int ii = 0; ii < 8; ++ii)
#pragma unroll
        for (int ww = 0; ww < 8; ++ww) acc[ii][ww] += zv[ii] * tv[ww];
    }
#pragma unroll
    for (int ii = 0; ii < 8; ++ii) {
      float* row = outp + (size_t)(h0 + hg2 * 8 + ii) * 256 + wp * 128 + wg * 8;
      *(float4*)&row[0] = make_float4(acc[ii][0], acc[ii][1], acc[ii][2], acc[ii][3]);
      *(float4*)&row[4] = make_float4(acc[ii][4], acc[ii][5], acc[ii][6], acc[ii][7]);
    }
  }
}

extern "C" void kernel_launch(void* const* d_in, const int* in_sizes, int n_in,
                              void* d_out, int out_size, void* d_ws, size_t ws_size,
                              hipStream_t stream) {
  const float* x   = (const float*)d_in[0];
  const float* w1r = (const float*)d_in[1];
  const float* w1i = (const float*)d_in[2];
  const float* w2r = (const float*)d_in[3];
  const float* w2i = (const float*)d_in[4];
  float* out = (float*)d_out;

  float2* Xm = (float2*)d_ws;          // 32*16*64*8 float2 = 2 MB
  float2* Am = Xm + 262144;            // 8*64*32*16 float2 = 2 MB
  float2* Pg = Am + 262144;            // 512*16*256 float2 = 16.8 MB

  k1a_wdft<<<dim3(2048), dim3(256), 0, stream>>>(x, Pg);
  k1b_hdft<<<dim3(512), dim3(256), 0, stream>>>(Pg, Xm);
  k2_mix<<<dim3(512), dim3(256), 0, stream>>>(Xm, w1r, w1i, w2r, w2i, Am);
  k3_inv<<<dim3(1024), dim3(256), 0, stream>>>(Am, out);
}